// Round 6
// baseline (216.034 us; speedup 1.0000x reference)
//
#include <hip/hip_runtime.h>
#include <hip/hip_bf16.h>

// Problem dims
#define BB 4
#define TT 2048
#define HH 16
#define SS 64
#define EE 1024

typedef __attribute__((ext_vector_type(8))) short short8;
typedef __attribute__((ext_vector_type(4))) short short4v;
typedef __attribute__((ext_vector_type(4))) float float4v;
typedef unsigned long long ull;

__device__ inline short f2bf(float f) {
    union { __hip_bfloat16 h; short s; } u;
    u.h = __float2bfloat16(f);
    return u.s;
}

__device__ inline unsigned pack_bf(float lo, float hi) {  // RNE pack
    return ((unsigned)(unsigned short)f2bf(hi) << 16) | (unsigned short)f2bf(lo);
}

__device__ inline unsigned pack_trunc(float lo, float hi) {  // truncation pack (2 ops)
    unsigned a = __builtin_bit_cast(unsigned, lo);
    unsigned b = __builtin_bit_cast(unsigned, hi);
    return (b & 0xFFFF0000u) | (a >> 16);
}

__device__ inline float4v mfma16(short8 a, short8 b, float4v c) {
    return __builtin_amdgcn_mfma_f32_16x16x32_bf16(a, b, c, 0, 0, 0);
}

#define LDSP(p) ((__attribute__((address_space(3))) void*)(p))
#define GLBP(p) ((const __attribute__((address_space(1))) void*)(p))

// ---------------------------------------------------------------------------
// Kernel 1: QKV projection, A=W / B=x. 512 blocks x 4 row-groups x 64 rows
// (block covers 256 consecutive rows): weight staging amortized 4x.
// sqrt(log2 e) folded into Wq,Wk (log2-domain scores).
// ---------------------------------------------------------------------------
__global__ __launch_bounds__(256) void k_qkv(
    const float* __restrict__ x, const float* __restrict__ Wk,
    const float* __restrict__ Wq, const float* __restrict__ Wv,
    short* __restrict__ qb, short* __restrict__ kb, short* __restrict__ vb)
{
    __shared__ __attribute__((aligned(16))) short lw[3][64][72];
    const int tid = threadIdx.x;
    const float sq = 0.21233045f;  // (1/1024^0.25) * sqrt(log2(e))

    for (int i = 0; i < 12; i++) {
        int u = tid + 256 * i;
        int w = u >> 10;
        int rem = u & 1023;
        int row = rem >> 4;
        int col = (rem & 15) * 4;
        const float* Wp = (w == 0) ? Wk : ((w == 1) ? Wq : Wv);
        float4v f = *reinterpret_cast<const float4v*>(Wp + row * 64 + col);
        float sc = (w == 2) ? 1.0f : sq;
        short4v s4;
        s4.x = f2bf(f.x * sc); s4.y = f2bf(f.y * sc);
        s4.z = f2bf(f.z * sc); s4.w = f2bf(f.w * sc);
        *reinterpret_cast<short4v*>(&lw[w][row][col]) = s4;
    }
    __syncthreads();

    const int wave = tid >> 6, lane = tid & 63;
    const int quad = lane >> 4, m = lane & 15;

    for (int rg = 0; rg < 4; rg++) {
        const long r0 = (long)blockIdx.x * 256 + rg * 64 + wave * 16;  // 16 rows/wave
        const int bt = (int)(r0 >> 4);
        const int b = bt >> 11, t = bt & 2047;

        const float* xrow = x + (r0 + m) * 64;
        short8 af[2];
        for (int ks = 0; ks < 2; ks++) {
            float4v f0 = *reinterpret_cast<const float4v*>(xrow + ks * 32 + quad * 8);
            float4v f1 = *reinterpret_cast<const float4v*>(xrow + ks * 32 + quad * 8 + 4);
            short8 a;
            a[0] = f2bf(f0.x); a[1] = f2bf(f0.y); a[2] = f2bf(f0.z); a[3] = f2bf(f0.w);
            a[4] = f2bf(f1.x); a[5] = f2bf(f1.y); a[6] = f2bf(f1.z); a[7] = f2bf(f1.w);
            af[ks] = a;
        }

        const long tb = ((long)(b * 16 + m) * 2048 + t) * 64;  // row base for head m
        for (int w = 0; w < 3; w++) {
            short* dst = (w == 0) ? kb : ((w == 1) ? qb : vb);
            for (int c = 0; c < 4; c++) {
                float4v acc = {0.f, 0.f, 0.f, 0.f};
                for (int ks = 0; ks < 2; ks++) {
                    short8 wf = *reinterpret_cast<const short8*>(&lw[w][c * 16 + m][ks * 32 + quad * 8]);
                    acc = mfma16(wf, af[ks], acc);  // A=W, B=x
                }
                unsigned lo = pack_bf(acc[0], acc[1]);
                unsigned hi = pack_bf(acc[2], acc[3]);
                ull wq = (ull)lo | ((ull)hi << 32);
                *reinterpret_cast<ull*>(dst + tb + c * 16 + quad * 4) = wq;
            }
        }
    }
}

// ---------------------------------------------------------------------------
// Kernel 2: prep (unchanged): V -> V^T [bh][s][t]; Wu -> bf16.
// ---------------------------------------------------------------------------
__global__ __launch_bounds__(256) void k_prep(
    const short* __restrict__ vb, short* __restrict__ vtb,
    const float* __restrict__ Wu, short* __restrict__ wub)
{
    __shared__ short lt[64][65];
    const int bid = blockIdx.x;
    const int tid = threadIdx.x;
    if (bid < 2048) {
        int bh = bid >> 5, tb = bid & 31;
        const short* src = vb + ((long)bh * 2048 + tb * 64) * 64;
        for (int i = 0; i < 2; i++) {
            int u = tid + 256 * i;
            int row = u >> 3, seg = u & 7;
            short8 d = *reinterpret_cast<const short8*>(src + row * 64 + seg * 8);
            for (int j = 0; j < 8; j++) lt[seg * 8 + j][row] = d[j];
        }
        __syncthreads();
        short* dst = vtb + (long)bh * 64 * 2048 + tb * 64;
        for (int i = 0; i < 2; i++) {
            int u = tid + 256 * i;
            int srow = u >> 3, seg = u & 7;
            short8 d;
            for (int j = 0; j < 8; j++) d[j] = lt[srow][seg * 8 + j];
            *reinterpret_cast<short8*>(dst + (long)srow * 2048 + seg * 8) = d;
        }
    } else {
        int cb = bid - 2048;
        long base = (long)cb * 4096;
        for (int i = 0; i < 4; i++) {
            long e = base + (long)tid * 4 + (long)i * 1024;
            float4v f = *reinterpret_cast<const float4v*>(Wu + e);
            short4v s;
            s.x = f2bf(f.x); s.y = f2bf(f.y); s.z = f2bf(f.z); s.w = f2bf(f.w);
            *reinterpret_cast<short4v*>(wub + e) = s;
        }
    }
}

// ---------------------------------------------------------------------------
// Kernel 3: attention. Double-buffered, 1 barrier/kt. Phase-split pipeline:
// all QK MFMAs (16 indep chains) -> per-sub exp/pack/PV (4 indep chains).
// l-sums in VALU from TRUNCATED packed P (bias cancels in P/l ratio);
// per-lane partials hold 16 keys -> cross-quad shfl_xor(16,32) in epilogue.
// ---------------------------------------------------------------------------
__global__ __launch_bounds__(256, 2) void k_attn(
    const short* __restrict__ qb, const short* __restrict__ kb,
    const short* __restrict__ vtb, short* __restrict__ ob)
{
    __shared__ __attribute__((aligned(16))) short kt_s[2][4096];
    __shared__ __attribute__((aligned(16))) short vt_s[2][4096];

    const int tid = threadIdx.x;
    const int wave = tid >> 6, lane = tid & 63;
    const int quad = lane >> 4, m = lane & 15;
    const int qblk = blockIdx.x, bh = blockIdx.y;
    const int q0 = qblk * 256;
    const long qoff = (long)bh * 2048 * 64;

    const short* kbase = kb + qoff;
    const short* vtbase = vtb + (long)bh * 64 * 2048;

    short8 qf[4][2];
    for (int sub = 0; sub < 4; sub++) {
        const short* qrow = qb + qoff + (long)(q0 + wave * 64 + sub * 16 + m) * 64;
        qf[sub][0] = *reinterpret_cast<const short8*>(qrow + quad * 8);
        qf[sub][1] = *reinterpret_cast<const short8*>(qrow + 32 + quad * 8);
    }

    float l[4] = {0.f, 0.f, 0.f, 0.f};
    float4v oacc[4][4];
    for (int s = 0; s < 4; s++)
        for (int c = 0; c < 4; c++) oacc[s][c] = (float4v){0.f, 0.f, 0.f, 0.f};

    // --- prologue: stage tile 0 into buffer 0 ---
    for (int i = 0; i < 2; i++) {
        int u = i * 256 + tid;
        int row = u >> 3;
        int cb = (u & 7) ^ (row & 7);
        const short* gp = kbase + (long)row * 64 + cb * 8;
        short* lp = &kt_s[0][(i * 256 + wave * 64) * 8];
        __builtin_amdgcn_global_load_lds(GLBP(gp), LDSP(lp), 16, 0, 0);
    }
    for (int i = 0; i < 2; i++) {
        int g = i * 256 + tid;
        int d = g >> 3, a = g & 7;
        union { short8 v; ull u[2]; } uv;
        uv.v = *reinterpret_cast<const short8*>(vtbase + (long)d * 2048 + a * 8);
        for (int h = 0; h < 2; h++) {
            int key0 = a * 8 + 4 * h;
            int c = key0 >> 4, qk = (key0 >> 2) & 3;
            int kk = (c >> 1) * 32 + qk * 8 + (c & 1) * 4;
            int idx = d * 64 + (((kk >> 3) ^ (d & 7)) * 8) + (kk & 7);
            *reinterpret_cast<ull*>(&vt_s[0][idx]) = uv.u[h];
        }
    }

    int p = 0;
    for (int kt = 0; kt < 32; kt++) {
        __syncthreads();  // buf[p] staged; everyone done reading buf[p^1]

        const bool pref = (kt < 31);
        union { short8 v; ull u[2]; } vreg[2];
        if (pref) {
            for (int i = 0; i < 2; i++) {
                int u = i * 256 + tid;
                int row = u >> 3;
                int cb = (u & 7) ^ (row & 7);
                const short* gp = kbase + (long)((kt + 1) * 64 + row) * 64 + cb * 8;
                short* lp = &kt_s[p ^ 1][(i * 256 + wave * 64) * 8];
                __builtin_amdgcn_global_load_lds(GLBP(gp), LDSP(lp), 16, 0, 0);
            }
            for (int i = 0; i < 2; i++) {
                int g = i * 256 + tid;
                int d = g >> 3, a = g & 7;
                vreg[i].v = *reinterpret_cast<const short8*>(
                    vtbase + (long)d * 2048 + (kt + 1) * 64 + a * 8);
            }
        }

        // K fragments
        short8 kf[4][2];
        for (int c = 0; c < 4; c++)
            for (int ks = 0; ks < 2; ks++)
                kf[c][ks] = *reinterpret_cast<const short8*>(
                    &kt_s[p][(c * 16 + m) * 64 + (((ks * 4 + quad) ^ (m & 7)) * 8)]);

        // ---- phase 1: ALL QK MFMAs (16 independent 2-chains) ----
        float4v st[4][4];
        for (int sub = 0; sub < 4; sub++)
            for (int c = 0; c < 4; c++) {
                float4v z = {0.f, 0.f, 0.f, 0.f};
                z = mfma16(kf[c][0], qf[sub][0], z);
                st[sub][c] = mfma16(kf[c][1], qf[sub][1], z);
            }

        // V fragments (kf now dead)
        short8 vfr[4][2];
        for (int c2 = 0; c2 < 4; c2++)
            for (int ks = 0; ks < 2; ks++)
                vfr[c2][ks] = *reinterpret_cast<const short8*>(
                    &vt_s[p][(c2 * 16 + m) * 64 + (((ks * 4 + quad) ^ (m & 7)) * 8)]);

        // ---- phase 2/3 per sub: exp -> trunc-pack -> l-sum (VALU) -> PV ----
        for (int sub = 0; sub < 4; sub++) {
            __attribute__((aligned(16))) unsigned pp[8];
            for (int c = 0; c < 4; c++) {
                float e0 = __builtin_amdgcn_exp2f(st[sub][c][0]);
                float e1 = __builtin_amdgcn_exp2f(st[sub][c][1]);
                float e2 = __builtin_amdgcn_exp2f(st[sub][c][2]);
                float e3 = __builtin_amdgcn_exp2f(st[sub][c][3]);
                pp[c * 2]     = pack_trunc(e0, e1);
                pp[c * 2 + 1] = pack_trunc(e2, e3);
            }
            float ls = 0.f;
            for (int i = 0; i < 8; i++) {
                float flo = __builtin_bit_cast(float, pp[i] << 16);
                float fhi = __builtin_bit_cast(float, pp[i] & 0xFFFF0000u);
                ls += flo + fhi;
            }
            l[sub] += ls;   // partial: this lane's 16 keys only (see epilogue)
            const short8* pf = reinterpret_cast<const short8*>(pp);
            for (int ks = 0; ks < 2; ks++)
                for (int c2 = 0; c2 < 4; c2++)
                    oacc[sub][c2] = mfma16(vfr[c2][ks], pf[ks], oacc[sub][c2]);
        }

        if (pref) {
            for (int i = 0; i < 2; i++) {
                int g = i * 256 + tid;
                int d = g >> 3, a = g & 7;
                for (int h = 0; h < 2; h++) {
                    int key0 = a * 8 + 4 * h;
                    int c = key0 >> 4, qk = (key0 >> 2) & 3;
                    int kk = (c >> 1) * 32 + qk * 8 + (c & 1) * 4;
                    int idx = d * 64 + (((kk >> 3) ^ (d & 7)) * 8) + (kk & 7);
                    *reinterpret_cast<ull*>(&vt_s[p ^ 1][idx]) = vreg[i].u[h];
                }
            }
        }
        p ^= 1;
    }

    // --- epilogue: cross-quad l reduction (lanes m, m+16, m+32, m+48) ---
    const int b = bh >> 4, h = bh & 15;
    for (int sub = 0; sub < 4; sub++) {
        float lv = l[sub];
        lv += __shfl_xor(lv, 16);
        lv += __shfl_xor(lv, 32);
        float li = 1.0f / lv;
        int t = q0 + wave * 64 + sub * 16 + m;
        long rowbase = (((long)(b * 2048 + t)) * 16 + h) * 64;
        for (int c2 = 0; c2 < 4; c2++) {
            unsigned w0 = pack_bf(oacc[sub][c2][0] * li, oacc[sub][c2][1] * li);
            unsigned w1 = pack_bf(oacc[sub][c2][2] * li, oacc[sub][c2][3] * li);
            ull wq = (ull)w0 | ((ull)w1 << 32);
            *reinterpret_cast<ull*>(ob + rowbase + c2 * 16 + quad * 4) = wq;
        }
    }
}

// ---------------------------------------------------------------------------
// Kernel 4: output projection, double-buffered DMA staging, 1 barrier/kt.
// ---------------------------------------------------------------------------
__global__ __launch_bounds__(256) void k_out(
    const short* __restrict__ ob, const short* __restrict__ wub,
    const float* __restrict__ bu, float* __restrict__ y)
{
    __shared__ __attribute__((aligned(16))) short a_s[2][8192];  // [128][64] swizzled
    __shared__ __attribute__((aligned(16))) short b_s[2][8192];

    const int tid = threadIdx.x;
    const int wave = tid >> 6, lane = tid & 63;
    const int quad = lane >> 4, m = lane & 15;
    const int nb = blockIdx.x, mb = blockIdx.y;
    const long mbase = (long)mb * 128;
    const int nbase = nb * 128;
    const int wm = (wave & 1) * 64, wn = (wave >> 1) * 64;

    float4v acc[4][4];
    for (int i = 0; i < 4; i++)
        for (int j = 0; j < 4; j++) acc[i][j] = (float4v){0.f, 0.f, 0.f, 0.f};

    // prologue: stage kt=0 -> buf0
    for (int i = 0; i < 4; i++) {
        int u = i * 256 + tid;
        int row = u >> 3;
        int c = (u & 7) ^ (row & 7);
        const short* gpA = ob + (mbase + row) * 1024 + c * 8;
        const short* gpB = wub + (long)(nbase + row) * 1024 + c * 8;
        short* lpA = &a_s[0][(i * 256 + wave * 64) * 8];
        short* lpB = &b_s[0][(i * 256 + wave * 64) * 8];
        __builtin_amdgcn_global_load_lds(GLBP(gpA), LDSP(lpA), 16, 0, 0);
        __builtin_amdgcn_global_load_lds(GLBP(gpB), LDSP(lpB), 16, 0, 0);
    }

    int p = 0;
    for (int kt = 0; kt < 16; kt++) {
        __syncthreads();
        if (kt < 15) {
            for (int i = 0; i < 4; i++) {
                int u = i * 256 + tid;
                int row = u >> 3;
                int c = (u & 7) ^ (row & 7);
                const short* gpA = ob + (mbase + row) * 1024 + (kt + 1) * 64 + c * 8;
                const short* gpB = wub + (long)(nbase + row) * 1024 + (kt + 1) * 64 + c * 8;
                short* lpA = &a_s[p ^ 1][(i * 256 + wave * 64) * 8];
                short* lpB = &b_s[p ^ 1][(i * 256 + wave * 64) * 8];
                __builtin_amdgcn_global_load_lds(GLBP(gpA), LDSP(lpA), 16, 0, 0);
                __builtin_amdgcn_global_load_lds(GLBP(gpB), LDSP(lpB), 16, 0, 0);
            }
        }
        for (int ks = 0; ks < 2; ks++) {
            short8 af[4], bf[4];
            for (int i = 0; i < 4; i++)
                af[i] = *reinterpret_cast<const short8*>(
                    &a_s[p][(wm + i * 16 + m) * 64 + (((ks * 4 + quad) ^ (m & 7)) * 8)]);
            for (int j = 0; j < 4; j++)
                bf[j] = *reinterpret_cast<const short8*>(
                    &b_s[p][(wn + j * 16 + m) * 64 + (((ks * 4 + quad) ^ (m & 7)) * 8)]);
            for (int i = 0; i < 4; i++)
                for (int j = 0; j < 4; j++)
                    acc[i][j] = mfma16(af[i], bf[j], acc[i][j]);
        }
        p ^= 1;
    }

    for (int j = 0; j < 4; j++) {
        int o = nbase + wn + j * 16 + m;
        float bias = bu[o];
        for (int i = 0; i < 4; i++) {
            for (int r = 0; r < 4; r++) {
                long row = mbase + wm + i * 16 + quad * 4 + r;
                y[row * 1024 + o] = acc[i][j][r] + bias;
            }
        }
    }
}

// ---------------------------------------------------------------------------
extern "C" void kernel_launch(void* const* d_in, const int* in_sizes, int n_in,
                              void* d_out, int out_size, void* d_ws, size_t ws_size,
                              hipStream_t stream)
{
    const float* x  = (const float*)d_in[0];
    const float* Wk = (const float*)d_in[1];
    const float* Wq = (const float*)d_in[2];
    const float* Wv = (const float*)d_in[3];
    const float* Wu = (const float*)d_in[4];
    const float* bu = (const float*)d_in[5];
    float* y = (float*)d_out;

    char* ws = (char*)d_ws;
    const size_t SEG = 16777216;  // 16 MiB
    short* qb  = (short*)(ws);
    short* kb  = (short*)(ws + 1 * SEG);
    short* vb  = (short*)(ws + 2 * SEG);
    short* vtb = (short*)(ws + 3 * SEG);
    short* ob  = (short*)(ws + 4 * SEG);
    short* wub = (short*)(ws + 5 * SEG);

    hipLaunchKernelGGL(k_qkv, dim3(512), dim3(256), 0, stream, x, Wk, Wq, Wv, qb, kb, vb);
    hipLaunchKernelGGL(k_prep, dim3(2304), dim3(256), 0, stream, vb, vtb, Wu, wub);
    hipLaunchKernelGGL(k_attn, dim3(8, 64), dim3(256), 0, stream, qb, kb, vtb, ob);
    hipLaunchKernelGGL(k_out, dim3(8, 64), dim3(256), 0, stream, ob, wub, bu, y);
}

// Round 7
// 211.072 us; speedup vs baseline: 1.0235x; 1.0235x over previous
//
#include <hip/hip_runtime.h>
#include <hip/hip_bf16.h>

// Problem dims
#define BB 4
#define TT 2048
#define HH 16
#define SS 64
#define EE 1024

typedef __attribute__((ext_vector_type(8))) short short8;
typedef __attribute__((ext_vector_type(4))) short short4v;
typedef __attribute__((ext_vector_type(4))) float float4v;
typedef unsigned long long ull;

__device__ inline short f2bf(float f) {
    union { __hip_bfloat16 h; short s; } u;
    u.h = __float2bfloat16(f);
    return u.s;
}

__device__ inline unsigned pack_bf(float lo, float hi) {  // RNE pack
    return ((unsigned)(unsigned short)f2bf(hi) << 16) | (unsigned short)f2bf(lo);
}

__device__ inline unsigned pack_trunc(float lo, float hi) {  // truncation pack (2 ops)
    unsigned a = __builtin_bit_cast(unsigned, lo);
    unsigned b = __builtin_bit_cast(unsigned, hi);
    return (b & 0xFFFF0000u) | (a >> 16);
}

__device__ inline float4v mfma16(short8 a, short8 b, float4v c) {
    return __builtin_amdgcn_mfma_f32_16x16x32_bf16(a, b, c, 0, 0, 0);
}

#define LDSP(p) ((__attribute__((address_space(3))) void*)(p))
#define GLBP(p) ((const __attribute__((address_space(1))) void*)(p))

// ---------------------------------------------------------------------------
// Kernel 1: QKV projection, A=W / B=x. q/k/v output TOKEN-MAJOR [b][t][h][s]:
// each wave computes one full token (16 heads x 64 s = contiguous 2KB row),
// so stores are dense. sqrt(log2 e) folded into Wq,Wk (log2-domain scores).
// ---------------------------------------------------------------------------
__global__ __launch_bounds__(256) void k_qkv(
    const float* __restrict__ x, const float* __restrict__ Wk,
    const float* __restrict__ Wq, const float* __restrict__ Wv,
    short* __restrict__ qb, short* __restrict__ kb, short* __restrict__ vb)
{
    __shared__ __attribute__((aligned(16))) short lw[3][64][72];
    const int tid = threadIdx.x;
    const float sq = 0.21233045f;  // (1/1024^0.25) * sqrt(log2(e))

    for (int i = 0; i < 12; i++) {
        int u = tid + 256 * i;
        int w = u >> 10;
        int rem = u & 1023;
        int row = rem >> 4;
        int col = (rem & 15) * 4;
        const float* Wp = (w == 0) ? Wk : ((w == 1) ? Wq : Wv);
        float4v f = *reinterpret_cast<const float4v*>(Wp + row * 64 + col);
        float sc = (w == 2) ? 1.0f : sq;
        short4v s4;
        s4.x = f2bf(f.x * sc); s4.y = f2bf(f.y * sc);
        s4.z = f2bf(f.z * sc); s4.w = f2bf(f.w * sc);
        *reinterpret_cast<short4v*>(&lw[w][row][col]) = s4;
    }
    __syncthreads();

    const int wave = tid >> 6, lane = tid & 63;
    const int quad = lane >> 4, m = lane & 15;

    for (int rg = 0; rg < 4; rg++) {
        const long r0 = (long)blockIdx.x * 256 + rg * 64 + wave * 16;  // 16 x-rows = 1 token
        const int bt = (int)(r0 >> 4);  // token index 0..8191

        const float* xrow = x + (r0 + m) * 64;  // lane m = head m of token bt
        short8 af[2];
        for (int ks = 0; ks < 2; ks++) {
            float4v f0 = *reinterpret_cast<const float4v*>(xrow + ks * 32 + quad * 8);
            float4v f1 = *reinterpret_cast<const float4v*>(xrow + ks * 32 + quad * 8 + 4);
            short8 a;
            a[0] = f2bf(f0.x); a[1] = f2bf(f0.y); a[2] = f2bf(f0.z); a[3] = f2bf(f0.w);
            a[4] = f2bf(f1.x); a[5] = f2bf(f1.y); a[6] = f2bf(f1.z); a[7] = f2bf(f1.w);
            af[ks] = a;
        }

        const long tbase = (long)bt * 1024 + m * 64;  // token-major row, head m
        for (int w = 0; w < 3; w++) {
            short* dst = (w == 0) ? kb : ((w == 1) ? qb : vb);
            for (int c = 0; c < 4; c++) {
                float4v acc = {0.f, 0.f, 0.f, 0.f};
                for (int ks = 0; ks < 2; ks++) {
                    short8 wf = *reinterpret_cast<const short8*>(&lw[w][c * 16 + m][ks * 32 + quad * 8]);
                    acc = mfma16(wf, af[ks], acc);  // A=W, B=x
                }
                unsigned lo = pack_bf(acc[0], acc[1]);
                unsigned hi = pack_bf(acc[2], acc[3]);
                ull wq = (ull)lo | ((ull)hi << 32);
                *reinterpret_cast<ull*>(dst + tbase + c * 16 + quad * 4) = wq;
            }
        }
    }
}

// ---------------------------------------------------------------------------
// Kernel 2: prep. V [b][t][h][s] -> V^T [bh][s][t]; Wu -> bf16.
// ---------------------------------------------------------------------------
__global__ __launch_bounds__(256) void k_prep(
    const short* __restrict__ vb, short* __restrict__ vtb,
    const float* __restrict__ Wu, short* __restrict__ wub)
{
    __shared__ short lt[64][65];
    const int bid = blockIdx.x;
    const int tid = threadIdx.x;
    if (bid < 2048) {
        int bh = bid >> 5, tb = bid & 31;
        int b = bh >> 4, h = bh & 15;
        const short* src = vb + ((long)(b * 2048 + tb * 64)) * 1024 + h * 64;
        for (int i = 0; i < 2; i++) {
            int u = tid + 256 * i;
            int row = u >> 3, seg = u & 7;   // row = token within tile
            short8 d = *reinterpret_cast<const short8*>(src + (long)row * 1024 + seg * 8);
            for (int j = 0; j < 8; j++) lt[seg * 8 + j][row] = d[j];
        }
        __syncthreads();
        short* dst = vtb + (long)bh * 64 * 2048 + tb * 64;
        for (int i = 0; i < 2; i++) {
            int u = tid + 256 * i;
            int srow = u >> 3, seg = u & 7;
            short8 d;
            for (int j = 0; j < 8; j++) d[j] = lt[srow][seg * 8 + j];
            *reinterpret_cast<short8*>(dst + (long)srow * 2048 + seg * 8) = d;
        }
    } else {
        int cb = bid - 2048;
        long base = (long)cb * 4096;
        for (int i = 0; i < 4; i++) {
            long e = base + (long)tid * 4 + (long)i * 1024;
            float4v f = *reinterpret_cast<const float4v*>(Wu + e);
            short4v s;
            s.x = f2bf(f.x); s.y = f2bf(f.y); s.z = f2bf(f.z); s.w = f2bf(f.w);
            *reinterpret_cast<short4v*>(wub + e) = s;
        }
    }
}

// ---------------------------------------------------------------------------
// Kernel 3: attention (R3-verified core). Double-buffered, 1 barrier/kt.
// Interleaved per-sub QK->exp->PV; l-sums via ones-MFMA on truncated P
// (bias cancels in P/l). q/k token-major [b][t][h][s]; V^T [bh][s][t].
// ---------------------------------------------------------------------------
__global__ __launch_bounds__(256, 2) void k_attn(
    const short* __restrict__ qb, const short* __restrict__ kb,
    const short* __restrict__ vtb, short* __restrict__ ob)
{
    __shared__ __attribute__((aligned(16))) short kt_s[2][4096];
    __shared__ __attribute__((aligned(16))) short vt_s[2][4096];

    const int tid = threadIdx.x;
    const int wave = tid >> 6, lane = tid & 63;
    const int quad = lane >> 4, m = lane & 15;
    const int qblk = blockIdx.x, bh = blockIdx.y;
    const int q0 = qblk * 256;
    const int b = bh >> 4, h = bh & 15;

    const short* kbase = kb + (long)b * 2048 * 1024 + h * 64;   // + t*1024
    const short* vtbase = vtb + (long)bh * 64 * 2048;

    short8 qf[4][2];
    for (int sub = 0; sub < 4; sub++) {
        const short* qrow = qb + ((long)(b * 2048 + q0 + wave * 64 + sub * 16 + m)) * 1024 + h * 64;
        qf[sub][0] = *reinterpret_cast<const short8*>(qrow + quad * 8);
        qf[sub][1] = *reinterpret_cast<const short8*>(qrow + 32 + quad * 8);
    }

    const short8 ones = (short8)((short)0x3F80);  // bf16 1.0 x8

    float4v lacc[4];
    float4v oacc[4][4];
    for (int s = 0; s < 4; s++) {
        lacc[s] = (float4v){0.f, 0.f, 0.f, 0.f};
        for (int c = 0; c < 4; c++) oacc[s][c] = (float4v){0.f, 0.f, 0.f, 0.f};
    }

    // --- prologue: stage tile 0 into buffer 0 ---
    for (int i = 0; i < 2; i++) {
        int u = i * 256 + tid;
        int row = u >> 3;
        int cb = (u & 7) ^ (row & 7);
        const short* gp = kbase + (long)row * 1024 + cb * 8;
        short* lp = &kt_s[0][(i * 256 + wave * 64) * 8];
        __builtin_amdgcn_global_load_lds(GLBP(gp), LDSP(lp), 16, 0, 0);
    }
    for (int i = 0; i < 2; i++) {
        int g = i * 256 + tid;
        int d = g >> 3, a = g & 7;
        union { short8 v; ull u[2]; } uv;
        uv.v = *reinterpret_cast<const short8*>(vtbase + (long)d * 2048 + a * 8);
        for (int hh = 0; hh < 2; hh++) {
            int key0 = a * 8 + 4 * hh;
            int c = key0 >> 4, qk = (key0 >> 2) & 3;
            int kk = (c >> 1) * 32 + qk * 8 + (c & 1) * 4;
            int idx = d * 64 + (((kk >> 3) ^ (d & 7)) * 8) + (kk & 7);
            *reinterpret_cast<ull*>(&vt_s[0][idx]) = uv.u[hh];
        }
    }

    int p = 0;
    for (int kt = 0; kt < 32; kt++) {
        __syncthreads();  // buf[p] staged; everyone done reading buf[p^1]

        const bool pref = (kt < 31);
        union { short8 v; ull u[2]; } vreg[2];
        if (pref) {
            for (int i = 0; i < 2; i++) {
                int u = i * 256 + tid;
                int row = u >> 3;
                int cb = (u & 7) ^ (row & 7);
                const short* gp = kbase + (long)((kt + 1) * 64 + row) * 1024 + cb * 8;
                short* lp = &kt_s[p ^ 1][(i * 256 + wave * 64) * 8];
                __builtin_amdgcn_global_load_lds(GLBP(gp), LDSP(lp), 16, 0, 0);
            }
            for (int i = 0; i < 2; i++) {
                int g = i * 256 + tid;
                int d = g >> 3, a = g & 7;
                vreg[i].v = *reinterpret_cast<const short8*>(
                    vtbase + (long)d * 2048 + (kt + 1) * 64 + a * 8);
            }
        }

        // fragment reads from buf[p]
        short8 kf[4][2], vfr[4][2];
        for (int c = 0; c < 4; c++)
            for (int ks = 0; ks < 2; ks++)
                kf[c][ks] = *reinterpret_cast<const short8*>(
                    &kt_s[p][(c * 16 + m) * 64 + (((ks * 4 + quad) ^ (m & 7)) * 8)]);
        for (int c2 = 0; c2 < 4; c2++)
            for (int ks = 0; ks < 2; ks++)
                vfr[c2][ks] = *reinterpret_cast<const short8*>(
                    &vt_s[p][(c2 * 16 + m) * 64 + (((ks * 4 + quad) ^ (m & 7)) * 8)]);

        // ---- per-sub: QK -> exp -> trunc-pack -> l (ones-MFMA) -> PV ----
        for (int sub = 0; sub < 4; sub++) {
            float4v st[4];
            for (int c = 0; c < 4; c++) {
                float4v z = {0.f, 0.f, 0.f, 0.f};
                z = mfma16(kf[c][0], qf[sub][0], z);
                st[c] = mfma16(kf[c][1], qf[sub][1], z);
            }
            __attribute__((aligned(16))) unsigned pp[8];
            for (int c = 0; c < 4; c++) {
                float e0 = __builtin_amdgcn_exp2f(st[c][0]);
                float e1 = __builtin_amdgcn_exp2f(st[c][1]);
                float e2 = __builtin_amdgcn_exp2f(st[c][2]);
                float e3 = __builtin_amdgcn_exp2f(st[c][3]);
                pp[c * 2]     = pack_trunc(e0, e1);
                pp[c * 2 + 1] = pack_trunc(e2, e3);
            }
            const short8* pf = reinterpret_cast<const short8*>(pp);
            lacc[sub] = mfma16(ones, pf[0], lacc[sub]);  // row sums (bias-cancelling)
            lacc[sub] = mfma16(ones, pf[1], lacc[sub]);
            for (int ks = 0; ks < 2; ks++)
                for (int c2 = 0; c2 < 4; c2++)
                    oacc[sub][c2] = mfma16(vfr[c2][ks], pf[ks], oacc[sub][c2]);
        }

        if (pref) {
            for (int i = 0; i < 2; i++) {
                int g = i * 256 + tid;
                int d = g >> 3, a = g & 7;
                for (int hh = 0; hh < 2; hh++) {
                    int key0 = a * 8 + 4 * hh;
                    int c = key0 >> 4, qk = (key0 >> 2) & 3;
                    int kk = (c >> 1) * 32 + qk * 8 + (c & 1) * 4;
                    int idx = d * 64 + (((kk >> 3) ^ (d & 7)) * 8) + (kk & 7);
                    *reinterpret_cast<ull*>(&vt_s[p ^ 1][idx]) = vreg[i].u[hh];
                }
            }
        }
        p ^= 1;
    }

    // --- epilogue: ones-MFMA already reduced over all 64 keys ---
    for (int sub = 0; sub < 4; sub++) {
        float li = 1.0f / lacc[sub][0];
        int t = q0 + wave * 64 + sub * 16 + m;
        long rowbase = (((long)(b * 2048 + t)) * 16 + h) * 64;
        for (int c2 = 0; c2 < 4; c2++) {
            unsigned w0 = pack_bf(oacc[sub][c2][0] * li, oacc[sub][c2][1] * li);
            unsigned w1 = pack_bf(oacc[sub][c2][2] * li, oacc[sub][c2][3] * li);
            ull wq = (ull)w0 | ((ull)w1 << 32);
            *reinterpret_cast<ull*>(ob + rowbase + c2 * 16 + quad * 4) = wq;
        }
    }
}

// ---------------------------------------------------------------------------
// Kernel 4: output projection, double-buffered DMA staging, 1 barrier/kt.
// ---------------------------------------------------------------------------
__global__ __launch_bounds__(256) void k_out(
    const short* __restrict__ ob, const short* __restrict__ wub,
    const float* __restrict__ bu, float* __restrict__ y)
{
    __shared__ __attribute__((aligned(16))) short a_s[2][8192];  // [128][64] swizzled
    __shared__ __attribute__((aligned(16))) short b_s[2][8192];

    const int tid = threadIdx.x;
    const int wave = tid >> 6, lane = tid & 63;
    const int quad = lane >> 4, m = lane & 15;
    const int nb = blockIdx.x, mb = blockIdx.y;
    const long mbase = (long)mb * 128;
    const int nbase = nb * 128;
    const int wm = (wave & 1) * 64, wn = (wave >> 1) * 64;

    float4v acc[4][4];
    for (int i = 0; i < 4; i++)
        for (int j = 0; j < 4; j++) acc[i][j] = (float4v){0.f, 0.f, 0.f, 0.f};

    // prologue: stage kt=0 -> buf0
    for (int i = 0; i < 4; i++) {
        int u = i * 256 + tid;
        int row = u >> 3;
        int c = (u & 7) ^ (row & 7);
        const short* gpA = ob + (mbase + row) * 1024 + c * 8;
        const short* gpB = wub + (long)(nbase + row) * 1024 + c * 8;
        short* lpA = &a_s[0][(i * 256 + wave * 64) * 8];
        short* lpB = &b_s[0][(i * 256 + wave * 64) * 8];
        __builtin_amdgcn_global_load_lds(GLBP(gpA), LDSP(lpA), 16, 0, 0);
        __builtin_amdgcn_global_load_lds(GLBP(gpB), LDSP(lpB), 16, 0, 0);
    }

    int p = 0;
    for (int kt = 0; kt < 16; kt++) {
        __syncthreads();
        if (kt < 15) {
            for (int i = 0; i < 4; i++) {
                int u = i * 256 + tid;
                int row = u >> 3;
                int c = (u & 7) ^ (row & 7);
                const short* gpA = ob + (mbase + row) * 1024 + (kt + 1) * 64 + c * 8;
                const short* gpB = wub + (long)(nbase + row) * 1024 + (kt + 1) * 64 + c * 8;
                short* lpA = &a_s[p ^ 1][(i * 256 + wave * 64) * 8];
                short* lpB = &b_s[p ^ 1][(i * 256 + wave * 64) * 8];
                __builtin_amdgcn_global_load_lds(GLBP(gpA), LDSP(lpA), 16, 0, 0);
                __builtin_amdgcn_global_load_lds(GLBP(gpB), LDSP(lpB), 16, 0, 0);
            }
        }
        for (int ks = 0; ks < 2; ks++) {
            short8 af[4], bf[4];
            for (int i = 0; i < 4; i++)
                af[i] = *reinterpret_cast<const short8*>(
                    &a_s[p][(wm + i * 16 + m) * 64 + (((ks * 4 + quad) ^ (m & 7)) * 8)]);
            for (int j = 0; j < 4; j++)
                bf[j] = *reinterpret_cast<const short8*>(
                    &b_s[p][(wn + j * 16 + m) * 64 + (((ks * 4 + quad) ^ (m & 7)) * 8)]);
            for (int i = 0; i < 4; i++)
                for (int j = 0; j < 4; j++)
                    acc[i][j] = mfma16(af[i], bf[j], acc[i][j]);
        }
        p ^= 1;
    }

    for (int j = 0; j < 4; j++) {
        int o = nbase + wn + j * 16 + m;
        float bias = bu[o];
        for (int i = 0; i < 4; i++) {
            for (int r = 0; r < 4; r++) {
                long row = mbase + wm + i * 16 + quad * 4 + r;
                y[row * 1024 + o] = acc[i][j][r] + bias;
            }
        }
    }
}

// ---------------------------------------------------------------------------
extern "C" void kernel_launch(void* const* d_in, const int* in_sizes, int n_in,
                              void* d_out, int out_size, void* d_ws, size_t ws_size,
                              hipStream_t stream)
{
    const float* x  = (const float*)d_in[0];
    const float* Wk = (const float*)d_in[1];
    const float* Wq = (const float*)d_in[2];
    const float* Wv = (const float*)d_in[3];
    const float* Wu = (const float*)d_in[4];
    const float* bu = (const float*)d_in[5];
    float* y = (float*)d_out;

    char* ws = (char*)d_ws;
    const size_t SEG = 16777216;  // 16 MiB
    short* qb  = (short*)(ws);
    short* kb  = (short*)(ws + 1 * SEG);
    short* vb  = (short*)(ws + 2 * SEG);
    short* vtb = (short*)(ws + 3 * SEG);
    short* ob  = (short*)(ws + 4 * SEG);
    short* wub = (short*)(ws + 5 * SEG);

    hipLaunchKernelGGL(k_qkv, dim3(512), dim3(256), 0, stream, x, Wk, Wq, Wv, qb, kb, vb);
    hipLaunchKernelGGL(k_prep, dim3(2304), dim3(256), 0, stream, vb, vtb, Wu, wub);
    hipLaunchKernelGGL(k_attn, dim3(8, 64), dim3(256), 0, stream, qb, kb, vtb, ob);
    hipLaunchKernelGGL(k_out, dim3(8, 64), dim3(256), 0, stream, ob, wub, bu, y);
}